// Round 1
// baseline (938.056 us; speedup 1.0000x reference)
//
#include <hip/hip_runtime.h>

// BalRNN: B=32, T=64, IN=512, L=2, H=4096, K=64
// ws layout (floats):
//   xe   [T][H][B]   offset 0           (8,388,608 floats)
//   h0   [2][H][B]   offset 8,388,608   (2*131,072)
//   h1   [2][H][B]   offset 8,650,752   (2*131,072)
// state layout is [h][b] so a gather of one index = 128B contiguous across b.

constexpr int B_ = 32, T_ = 64, IN_ = 512, H_ = 4096, K_ = 64;
constexpr int HB_ = H_ * B_;            // 131072
constexpr int XE_ELEMS = T_ * HB_;      // 8388608

// ---------------------------------------------------------------------------
// xe[t][h][b] = sum_i w[h][i] * x[b][t][i]
// GEMM: M=H=4096 (m=h), N=T*B=2048 (n = t*32+b), K=IN=512
// tile 64x64, BK=16, 256 threads, thread tile 4x4
// ---------------------------------------------------------------------------
__global__ __launch_bounds__(256) void gemm_xe(const float* __restrict__ x,
                                               const float* __restrict__ w,
                                               float* __restrict__ xe) {
    __shared__ float As[16][64];
    __shared__ float Bs[16][64];
    const int tid = threadIdx.x;
    const int m0 = blockIdx.x * 64;     // 64 blocks in M
    const int n0 = blockIdx.y * 64;     // 32 blocks in N
    const int row = tid >> 2;           // 0..63
    const int kq  = tid & 3;            // 0..3  (float4 column within BK)

    const float* aSrc = w + (m0 + row) * IN_ + kq * 4;
    const int n = n0 + row;
    const float* bSrc = x + (n & 31) * (T_ * IN_) + (n >> 5) * IN_ + kq * 4;

    const int tm = (tid >> 4) * 4;      // 0..60
    const int tn = (tid & 15) * 4;      // 0..60

    float c[4][4] = {};

    for (int k0 = 0; k0 < IN_; k0 += 16) {
        float4 av = *(const float4*)(aSrc + k0);
        float4 bv = *(const float4*)(bSrc + k0);
        __syncthreads();
        As[kq * 4 + 0][row] = av.x; As[kq * 4 + 1][row] = av.y;
        As[kq * 4 + 2][row] = av.z; As[kq * 4 + 3][row] = av.w;
        Bs[kq * 4 + 0][row] = bv.x; Bs[kq * 4 + 1][row] = bv.y;
        Bs[kq * 4 + 2][row] = bv.z; Bs[kq * 4 + 3][row] = bv.w;
        __syncthreads();
#pragma unroll
        for (int k = 0; k < 16; ++k) {
            float4 a = *(const float4*)&As[k][tm];
            float4 b = *(const float4*)&Bs[k][tn];
            c[0][0] += a.x * b.x; c[0][1] += a.x * b.y; c[0][2] += a.x * b.z; c[0][3] += a.x * b.w;
            c[1][0] += a.y * b.x; c[1][1] += a.y * b.y; c[1][2] += a.y * b.z; c[1][3] += a.y * b.w;
            c[2][0] += a.z * b.x; c[2][1] += a.z * b.y; c[2][2] += a.z * b.z; c[2][3] += a.z * b.w;
            c[3][0] += a.w * b.x; c[3][1] += a.w * b.y; c[3][2] += a.w * b.z; c[3][3] += a.w * b.w;
        }
    }

    // write: element (m, n) -> xe[(n>>5)][m][(n&31)]; tn aligned 4, tile aligned 32
    const int nn = n0 + tn;
    const int tbase = nn >> 5;
    const int bb = nn & 31;
#pragma unroll
    for (int mi = 0; mi < 4; ++mi) {
        float4 v = make_float4(c[mi][0], c[mi][1], c[mi][2], c[mi][3]);
        *(float4*)(xe + tbase * HB_ + (m0 + tm + mi) * B_ + bb) = v;
    }
}

// ---------------------------------------------------------------------------
// Skewed step kernel at "time" t (t = 0..T):
//   part A (blocks 0..511,   if t <  T): h0(t)   = relu(xe[t] + S0 @ h0(t-1))
//   part B (blocks 512..1023,if t >= 1): h1(t-1) = relu(S1 @ h0(t-1) + S1 @ h1(t-2))
// One wave handles one output row h: lanes = (kh in {0,1}) x (b in 0..31).
// idx/val addresses are wave-uniform -> scalar loads; gather = 2x128B/instr.
// ---------------------------------------------------------------------------
__global__ __launch_bounds__(256) void step_kernel(
    const int*   __restrict__ idx0, const float* __restrict__ val0,
    const int*   __restrict__ idx1, const float* __restrict__ val1,
    const float* __restrict__ xe_t,
    const float* __restrict__ h0_rd, float* __restrict__ h0_wr,
    const float* __restrict__ h1_rd, float* __restrict__ h1_wr,
    float*       __restrict__ out_s,   // d_out + s*H ; lane adds b*(T*H) + h
    int doA, int doB) {
    __shared__ float lds[8 * 32];
    const int bid  = blockIdx.x;
    const int tid  = threadIdx.x;
    const int wid  = __builtin_amdgcn_readfirstlane(tid >> 6);
    const int lane = tid & 63;
    const int kh   = lane >> 5;   // which k-half this lane sums
    const int b    = lane & 31;

    if (bid < 512) {                       // ----- part A: layer 0 -----
        if (!doA) return;
        const int h_base = bid * 8;
#pragma unroll
        for (int rep = 0; rep < 2; ++rep) {
            const int h = h_base + wid * 2 + rep;
            const int*   ip = idx0 + h * K_;
            const float* vp = val0 + h * K_;
            float acc = 0.f;
#pragma unroll 8
            for (int k2 = 0; k2 < 32; ++k2) {
                const int   i0 = ip[k2], i1 = ip[k2 + 32];
                const float v0 = vp[k2], v1 = vp[k2 + 32];
                const int   myi = kh ? i1 : i0;
                const float myv = kh ? v1 : v0;
                acc += myv * h0_rd[myi * B_ + b];
            }
            acc += __shfl_xor(acc, 32);
            acc += xe_t[h * B_ + b];
            acc = fmaxf(acc, 0.f);
            if (kh == 0) h0_wr[h * B_ + b] = acc;
        }
    } else {                               // ----- part B: layer 1 -----
        if (!doB) return;
        const int h_base = (bid - 512) * 8;
#pragma unroll
        for (int rep = 0; rep < 2; ++rep) {
            const int h = h_base + wid * 2 + rep;
            const int*   ip = idx1 + h * K_;
            const float* vp = val1 + h * K_;
            float acc = 0.f;
#pragma unroll 8
            for (int k2 = 0; k2 < 32; ++k2) {
                const int   i0 = ip[k2], i1 = ip[k2 + 32];
                const float v0 = vp[k2], v1 = vp[k2 + 32];
                const int   myi = kh ? i1 : i0;
                const float myv = kh ? v1 : v0;
                const int   off = myi * B_ + b;
                acc += myv * (h0_rd[off] + h1_rd[off]);
            }
            acc += __shfl_xor(acc, 32);
            acc = fmaxf(acc, 0.f);
            if (kh == 0) {
                h1_wr[h * B_ + b] = acc;
                lds[(wid * 2 + rep) * 32 + b] = acc;
            }
        }
        __syncthreads();
        // transpose 8x32 tile: out[b][s][h_base+hl], 8 consecutive floats / 8 threads
        const int b_o = tid >> 3;   // 0..31
        const int hl  = tid & 7;    // 0..7
        out_s[b_o * (T_ * H_) + h_base + hl] = lds[hl * 32 + b_o];
    }
}

// h_final[l][b][h] from state buffers (state layout [h][b])
__global__ __launch_bounds__(256) void finalize(const float* __restrict__ h0s,
                                                const float* __restrict__ h1s,
                                                float* __restrict__ hf) {
    const int i = blockIdx.x * 256 + threadIdx.x;   // 0..262143
    const int l = i >> 17;                          // / (B*H)
    const int r = i & (HB_ - 1);
    const int b = r >> 12;                          // / H
    const int h = r & (H_ - 1);
    const float* s = l ? h1s : h0s;
    hf[i] = s[h * B_ + b];
}

extern "C" void kernel_launch(void* const* d_in, const int* in_sizes, int n_in,
                              void* d_out, int out_size, void* d_ws, size_t ws_size,
                              hipStream_t stream) {
    const float* x       = (const float*)d_in[0];
    const float* w_ih    = (const float*)d_in[1];
    const int*   hh_idx  = (const int*)d_in[2];
    const float* hh_vals = (const float*)d_in[3];
    float* out = (float*)d_out;
    float* ws  = (float*)d_ws;

    float* xe = ws;                       // [T][H][B]
    float* h0 = ws + XE_ELEMS;            // [2][H][B]
    float* h1 = h0 + 2 * HB_;             // [2][H][B]

    // zero the "t = -1" parity buffers (ws is poisoned before every launch)
    hipMemsetAsync(h0 + HB_, 0, HB_ * sizeof(float), stream);
    hipMemsetAsync(h1 + HB_, 0, HB_ * sizeof(float), stream);

    gemm_xe<<<dim3(64, 32), 256, 0, stream>>>(x, w_ih, xe);

    for (int t = 0; t <= T_; ++t) {
        const int doA = (t < T_) ? 1 : 0;
        const int doB = (t >= 1) ? 1 : 0;
        const int s = t - 1;
        const float* h0_rd = h0 + ((t - 1) & 1) * HB_;  // h0(t-1); t=0 -> zeroed buf
        float*       h0_wr = h0 + (t & 1) * HB_;        // h0(t)
        const float* h1_rd = h1 + (t & 1) * HB_;        // h1(t-2)
        float*       h1_wr = h1 + ((t - 1) & 1) * HB_;  // h1(t-1)
        step_kernel<<<1024, 256, 0, stream>>>(
            hh_idx, hh_vals, hh_idx + H_ * K_, hh_vals + H_ * K_,
            xe + (doA ? t : 0) * HB_,
            h0_rd, h0_wr, h1_rd, h1_wr,
            out + (doB ? s : 0) * H_,
            doA, doB);
    }

    // h_final: parity of t = T-1 = 63 -> buffer 1
    finalize<<<1024, 256, 0, stream>>>(h0 + ((T_ - 1) & 1) * HB_,
                                       h1 + ((T_ - 1) & 1) * HB_,
                                       out + B_ * T_ * H_);
}